// Round 2
// baseline (968.693 us; speedup 1.0000x reference)
//
#include <hip/hip_runtime.h>

// fp8 blockwise-quantized GEMM for MI355X (gfx950) — round 2
//   y = (fp8(x/sx)*sx) @ (fp8(w)*sw)^T
// Round-2 change: quant kernels store xq/wq in MFMA *fragment order*
// (2KB per (16-row x 128-k) fragment group, lane-major), so the GEMM reads
// A/B fragments directly from global memory with coalesced global_load_dwordx4
// (L2/LLC-resident) — no LDS tiles, no barriers in the K-loop (escapes the
// m97 barrier-drain plateau and the LDS-read-throughput bound).

typedef int   v4i __attribute__((ext_vector_type(4)));
typedef int   v8i __attribute__((ext_vector_type(8)));
typedef float v4f __attribute__((ext_vector_type(4)));

constexpr int M  = 8192;
constexpr int K  = 4096;
constexpr int N  = 4096;
constexpr int KB = K / 128;  // 32
constexpr int NB = N / 128;  // 32

// Fragment-order layout for a quantized matrix Q[R][K] (row-major logical):
//   group g = (rf, kb), rf = r>>4 (16-row band), kb = k>>7 (128-k band)
//   base = (rf*KB + kb) * 2048
//   lane l = q*16 + rr  (q = k-quad 0..3, rr = r&15)
//   j = 0/1 selects k-bytes [q*32, q*32+16) / [q*32+16, q*32+32)
//   byte addr = base + j*1024 + l*16 + (k&15)
// GEMM A/B fragment (16x16x128 f8f6f4): lane l holds row (l&15),
// k-bytes (l>>4)*32..+32  ->  lo16 = [base + l*16], hi16 = [base + 1024 + l*16].

// ---------------- activation blockwise quant (fragment-order output) -------
// 8 lanes per 128-elem block; each lane handles 16 consecutive elements.
__global__ __launch_bounds__(256) void quant_x_kernel(
    const float* __restrict__ x, unsigned char* __restrict__ xq,
    float* __restrict__ xs_t /* [KB][M] */) {
  const int tid = threadIdx.x;
  const long long blk = ((long long)blockIdx.x * 256 + tid) >> 3;  // over M*KB
  const int s = tid & 7;                                           // 0..7
  const int m  = (int)(blk >> 5);        // KB = 32
  const int kb = (int)(blk & (KB - 1));

  const float4* px = (const float4*)(x + blk * 128 + s * 16);
  float4 v0 = px[0], v1 = px[1], v2 = px[2], v3 = px[3];

  float ax = 0.f;
#define AMAX4(v) ax = fmaxf(ax, fmaxf(fmaxf(fabsf(v.x), fabsf(v.y)), fmaxf(fabsf(v.z), fabsf(v.w))))
  AMAX4(v0); AMAX4(v1); AMAX4(v2); AMAX4(v3);
#undef AMAX4
#pragma unroll
  for (int d = 4; d >= 1; d >>= 1) ax = fmaxf(ax, __shfl_xor(ax, d, 8));
  // match reference: scale = max(amax,1e-12)/448 (true divisions, RNE)
  const float scale = fmaxf(ax, 1e-12f) / 448.0f;

  int p0 = 0, p1 = 0, p2 = 0, p3 = 0;
  p0 = __builtin_amdgcn_cvt_pk_fp8_f32(v0.x / scale, v0.y / scale, p0, false);
  p0 = __builtin_amdgcn_cvt_pk_fp8_f32(v0.z / scale, v0.w / scale, p0, true);
  p1 = __builtin_amdgcn_cvt_pk_fp8_f32(v1.x / scale, v1.y / scale, p1, false);
  p1 = __builtin_amdgcn_cvt_pk_fp8_f32(v1.z / scale, v1.w / scale, p1, true);
  p2 = __builtin_amdgcn_cvt_pk_fp8_f32(v2.x / scale, v2.y / scale, p2, false);
  p2 = __builtin_amdgcn_cvt_pk_fp8_f32(v2.z / scale, v2.w / scale, p2, true);
  p3 = __builtin_amdgcn_cvt_pk_fp8_f32(v3.x / scale, v3.y / scale, p3, false);
  p3 = __builtin_amdgcn_cvt_pk_fp8_f32(v3.z / scale, v3.w / scale, p3, true);

  // fragment-order position: q = s>>1, j = s&1, rr = m&15
  const int q = s >> 1, j = s & 1, rr = m & 15;
  const long long base = ((long long)(m >> 4) * KB + kb) * 2048;
  *(v4i*)(xq + base + j * 1024 + (q * 16 + rr) * 16) = (v4i){p0, p1, p2, p3};

  if (s == 0) xs_t[(long long)kb * M + m] = scale;  // transposed scales
}

// ---------------- weight fp8 cast (fragment-order output) ----------------
// thread handles 16 consecutive k-bytes of one row.
__global__ __launch_bounds__(256) void quant_w_kernel(
    const float* __restrict__ w, unsigned char* __restrict__ wq) {
  const long long t = (long long)blockIdx.x * 256 + threadIdx.x;  // N*K/16
  const int grp = (int)(t >> 7);        // (nf, kb): nf = grp>>5, kb = grp&31
  const int idx = (int)(t & 127);
  const int l = idx >> 1, j = idx & 1;
  const int nf = grp >> 5, kb = grp & (KB - 1);
  const int n = nf * 16 + (l & 15);
  const int k = kb * 128 + (l >> 4) * 32 + j * 16;

  const float4* pw = (const float4*)(w + (long long)n * K + k);
  float4 v0 = pw[0], v1 = pw[1], v2 = pw[2], v3 = pw[3];
  int p0 = 0, p1 = 0, p2 = 0, p3 = 0;
  p0 = __builtin_amdgcn_cvt_pk_fp8_f32(v0.x, v0.y, p0, false);
  p0 = __builtin_amdgcn_cvt_pk_fp8_f32(v0.z, v0.w, p0, true);
  p1 = __builtin_amdgcn_cvt_pk_fp8_f32(v1.x, v1.y, p1, false);
  p1 = __builtin_amdgcn_cvt_pk_fp8_f32(v1.z, v1.w, p1, true);
  p2 = __builtin_amdgcn_cvt_pk_fp8_f32(v2.x, v2.y, p2, false);
  p2 = __builtin_amdgcn_cvt_pk_fp8_f32(v2.z, v2.w, p2, true);
  p3 = __builtin_amdgcn_cvt_pk_fp8_f32(v3.x, v3.y, p3, false);
  p3 = __builtin_amdgcn_cvt_pk_fp8_f32(v3.z, v3.w, p3, true);
  *(v4i*)(wq + (long long)grp * 2048 + j * 1024 + l * 16) = (v4i){p0, p1, p2, p3};
}

// ---------------- fragment-direct fp8 GEMM ----------------
// grid (N/128, M/128), 256 threads = 4 waves 2x2, wave tile 64x64.
// K-loop: barrier-free, fragments loaded direct from global (L2-resident),
// manually 2-deep software-pipelined.
__global__ __launch_bounds__(256, 2) void gemm_fp8_kernel(
    const unsigned char* __restrict__ xq, const unsigned char* __restrict__ wq,
    const float* __restrict__ xs_t /*[KB][M]*/,
    const float* __restrict__ wscale /*[NB][KB]*/,
    float* __restrict__ out) {
  __shared__ float Ssm[KB * 128];  // 16 KB combined scales [kb][row-of-mtile]

  const int tid   = threadIdx.x;
  const int ntile = blockIdx.x;  // 0..31
  const int mtile = blockIdx.y;  // 0..63
  const int wave  = tid >> 6;
  const int lane  = tid & 63;
  const int wm = wave >> 1, wn = wave & 1;
  const int l15 = lane & 15, quad = lane >> 4;

  // one-time combined scales: Ssm[kb*128 + r] = xs[mtile*128+r, kb] * wsc[ntile, kb]
  for (int i = tid; i < KB * 128; i += 256) {
    const int kb = i >> 7, r = i & 127;
    Ssm[i] = xs_t[(long long)kb * M + mtile * 128 + r] * wscale[ntile * KB + kb];
  }
  __syncthreads();  // only barrier in the kernel

  // fragment base pointers (lane offset folded in); f stride = KB*2048 = 64 KiB
  const unsigned char* pa0 =
      xq + ((long long)(mtile * 8 + wm * 4) * KB) * 2048 + lane * 16;
  const unsigned char* pb0 =
      wq + ((long long)(ntile * 8 + wn * 4) * KB) * 2048 + lane * 16;

  int soff[4];
#pragma unroll
  for (int f = 0; f < 4; ++f) soff[f] = wm * 64 + f * 16 + quad * 4;

  v4f acc[4][4];
#pragma unroll
  for (int f = 0; f < 4; ++f)
#pragma unroll
    for (int g = 0; g < 4; ++g) acc[f][g] = (v4f){0.f, 0.f, 0.f, 0.f};

  v4i aLo[2][4], aHi[2][4], bLo[2][4], bHi[2][4];

#define LOADK(kb, buf)                                                  \
  {                                                                     \
    const unsigned char* pa = pa0 + (long long)(kb) * 2048;             \
    const unsigned char* pb = pb0 + (long long)(kb) * 2048;             \
    _Pragma("unroll") for (int f = 0; f < 4; ++f) {                     \
      aLo[buf][f] = *(const v4i*)(pa + (long long)f * (KB * 2048));     \
      aHi[buf][f] = *(const v4i*)(pa + (long long)f * (KB * 2048) + 1024); \
      bLo[buf][f] = *(const v4i*)(pb + (long long)f * (KB * 2048));     \
      bHi[buf][f] = *(const v4i*)(pb + (long long)f * (KB * 2048) + 1024); \
    }                                                                   \
  }

  LOADK(0, 0);

  for (int kb = 0; kb < KB; ++kb) {
    const int cur = kb & 1;
    if (kb + 1 < KB) LOADK(kb + 1, cur ^ 1);

    v4f sx[4];
#pragma unroll
    for (int f = 0; f < 4; ++f) sx[f] = *(const v4f*)(Ssm + kb * 128 + soff[f]);

    v8i a[4], b[4];
#pragma unroll
    for (int f = 0; f < 4; ++f) {
      a[f][0] = aLo[cur][f][0]; a[f][1] = aLo[cur][f][1];
      a[f][2] = aLo[cur][f][2]; a[f][3] = aLo[cur][f][3];
      a[f][4] = aHi[cur][f][0]; a[f][5] = aHi[cur][f][1];
      a[f][6] = aHi[cur][f][2]; a[f][7] = aHi[cur][f][3];
      b[f][0] = bLo[cur][f][0]; b[f][1] = bLo[cur][f][1];
      b[f][2] = bLo[cur][f][2]; b[f][3] = bLo[cur][f][3];
      b[f][4] = bHi[cur][f][0]; b[f][5] = bHi[cur][f][1];
      b[f][6] = bHi[cur][f][2]; b[f][7] = bHi[cur][f][3];
    }

#pragma unroll
    for (int f = 0; f < 4; ++f) {
#pragma unroll
      for (int g = 0; g < 4; ++g) {
        const v4f z = (v4f){0.f, 0.f, 0.f, 0.f};
        // unit e8m0 scales (0x7F = 2^0): plain fp8 K=128 dot at MX rate
        v4f p = __builtin_amdgcn_mfma_scale_f32_16x16x128_f8f6f4(
            a[f], b[g], z, 0, 0, 0, 0x7f7f7f7f, 0, 0x7f7f7f7f);
        acc[f][g] += sx[f] * p;  // exact f32 combined scale per K=128 block
      }
    }
  }
#undef LOADK

  // epilogue: C/D layout col = lane&15, row = quad*4 + reg
#pragma unroll
  for (int f = 0; f < 4; ++f) {
#pragma unroll
    for (int r = 0; r < 4; ++r) {
      const long long row = mtile * 128 + wm * 64 + f * 16 + quad * 4 + r;
      float* po = out + row * N + ntile * 128 + wn * 64 + l15;
#pragma unroll
      for (int g = 0; g < 4; ++g) po[g * 16] = acc[f][g][r];
    }
  }
}

extern "C" void kernel_launch(void* const* d_in, const int* in_sizes, int n_in,
                              void* d_out, int out_size, void* d_ws, size_t ws_size,
                              hipStream_t stream) {
  const float* x   = (const float*)d_in[0];  // [M,K]
  const float* w   = (const float*)d_in[1];  // [N,K]
  const float* wsc = (const float*)d_in[2];  // [NB,KB]
  float* out = (float*)d_out;                // [M,N] f32

  unsigned char* ws = (unsigned char*)d_ws;
  unsigned char* xq = ws;                                      // 32 MB, frag-order
  unsigned char* wq = ws + (size_t)M * K;                      // 16 MB, frag-order
  float* xs_t = (float*)(ws + (size_t)M * K + (size_t)N * K);  // 1 MB [KB][M]

  quant_x_kernel<<<(M * KB * 8) / 256, 256, 0, stream>>>(x, xq, xs_t);
  quant_w_kernel<<<(int)(((long long)N * K / 16) / 256), 256, 0, stream>>>(w, wq);
  gemm_fp8_kernel<<<dim3(NB, M / 128), 256, 0, stream>>>(xq, wq, xs_t, wsc, out);
}

// Round 3
// 430.762 us; speedup vs baseline: 2.2488x; 2.2488x over previous
//
#include <hip/hip_runtime.h>

// fp8 blockwise-quantized GEMM for MI355X (gfx950) — round 3
//   y = (fp8(x/sx)*sx) @ (fp8(w)*sw)^T
// Round-3: back to the proven LDS-staging path (round-2's fragment-direct
// global reads are L2-BW-doomed and its dynamically-indexed reg arrays spilled
// to scratch: 2.27 GB WRITE_SIZE). New: 256x128 block tile / 128x64 wave tile
// (Fa=8 x Fb=4) -> 85 FLOP per LDS byte (machine balance ~89), with the
// fragment-order workspace layout so staging is contiguous 1KB DMAs and
// fragment ds_read_b128s need zero swizzle math.

typedef int   v4i __attribute__((ext_vector_type(4)));
typedef int   v8i __attribute__((ext_vector_type(8)));
typedef float v4f __attribute__((ext_vector_type(4)));

constexpr int M  = 8192;
constexpr int K  = 4096;
constexpr int N  = 4096;
constexpr int KB = K / 128;  // 32
constexpr int NB = N / 128;  // 32

#define GLOBAL_AS __attribute__((address_space(1)))
#define LDS_AS    __attribute__((address_space(3)))

__device__ __forceinline__ void async16(const void* g, void* l) {
  // 16B/lane global->LDS DMA; LDS dest = wave-uniform base (+ lane*16 by HW)
  __builtin_amdgcn_global_load_lds((const GLOBAL_AS void*)g, (LDS_AS void*)l, 16, 0, 0);
}

// Fragment-order layout for quantized Q[R][K]:
//   group (rf = r>>4, kb = k>>7) at base (rf*KB + kb)*2048
//   lane l = (k-quad)*16 + (r&15); lo16 @ base + l*16, hi16 @ base + 1024 + l*16
// matches the 16x16x128 f8f6f4 A/B operand layout (HW-validated rounds 1-2).

// ---------------- activation blockwise quant (fragment-order output) -------
__global__ __launch_bounds__(256) void quant_x_kernel(
    const float* __restrict__ x, unsigned char* __restrict__ xq,
    float* __restrict__ xs_t /* [KB][M] */) {
  const int tid = threadIdx.x;
  const long long blk = ((long long)blockIdx.x * 256 + tid) >> 3;  // over M*KB
  const int s = tid & 7;
  const int m  = (int)(blk >> 5);        // KB = 32
  const int kb = (int)(blk & (KB - 1));

  const float4* px = (const float4*)(x + blk * 128 + s * 16);
  float4 v0 = px[0], v1 = px[1], v2 = px[2], v3 = px[3];

  float ax = 0.f;
#define AMAX4(v) ax = fmaxf(ax, fmaxf(fmaxf(fabsf(v.x), fabsf(v.y)), fmaxf(fabsf(v.z), fabsf(v.w))))
  AMAX4(v0); AMAX4(v1); AMAX4(v2); AMAX4(v3);
#undef AMAX4
#pragma unroll
  for (int d = 4; d >= 1; d >>= 1) ax = fmaxf(ax, __shfl_xor(ax, d, 8));
  const float scale = fmaxf(ax, 1e-12f) / 448.0f;  // matches reference RNE path

  int p0 = 0, p1 = 0, p2 = 0, p3 = 0;
  p0 = __builtin_amdgcn_cvt_pk_fp8_f32(v0.x / scale, v0.y / scale, p0, false);
  p0 = __builtin_amdgcn_cvt_pk_fp8_f32(v0.z / scale, v0.w / scale, p0, true);
  p1 = __builtin_amdgcn_cvt_pk_fp8_f32(v1.x / scale, v1.y / scale, p1, false);
  p1 = __builtin_amdgcn_cvt_pk_fp8_f32(v1.z / scale, v1.w / scale, p1, true);
  p2 = __builtin_amdgcn_cvt_pk_fp8_f32(v2.x / scale, v2.y / scale, p2, false);
  p2 = __builtin_amdgcn_cvt_pk_fp8_f32(v2.z / scale, v2.w / scale, p2, true);
  p3 = __builtin_amdgcn_cvt_pk_fp8_f32(v3.x / scale, v3.y / scale, p3, false);
  p3 = __builtin_amdgcn_cvt_pk_fp8_f32(v3.z / scale, v3.w / scale, p3, true);

  const int q = s >> 1, j = s & 1, rr = m & 15;
  const long long base = ((long long)(m >> 4) * KB + kb) * 2048;
  *(v4i*)(xq + base + j * 1024 + (q * 16 + rr) * 16) = (v4i){p0, p1, p2, p3};

  if (s == 0) xs_t[(long long)kb * M + m] = scale;
}

// ---------------- weight fp8 cast (fragment-order output) ----------------
__global__ __launch_bounds__(256) void quant_w_kernel(
    const float* __restrict__ w, unsigned char* __restrict__ wq) {
  const long long t = (long long)blockIdx.x * 256 + threadIdx.x;  // N*K/16
  const int grp = (int)(t >> 7);
  const int idx = (int)(t & 127);
  const int l = idx >> 1, j = idx & 1;
  const int nf = grp >> 5, kb = grp & (KB - 1);
  const int n = nf * 16 + (l & 15);
  const int k = kb * 128 + (l >> 4) * 32 + j * 16;

  const float4* pw = (const float4*)(w + (long long)n * K + k);
  float4 v0 = pw[0], v1 = pw[1], v2 = pw[2], v3 = pw[3];
  int p0 = 0, p1 = 0, p2 = 0, p3 = 0;
  p0 = __builtin_amdgcn_cvt_pk_fp8_f32(v0.x, v0.y, p0, false);
  p0 = __builtin_amdgcn_cvt_pk_fp8_f32(v0.z, v0.w, p0, true);
  p1 = __builtin_amdgcn_cvt_pk_fp8_f32(v1.x, v1.y, p1, false);
  p1 = __builtin_amdgcn_cvt_pk_fp8_f32(v1.z, v1.w, p1, true);
  p2 = __builtin_amdgcn_cvt_pk_fp8_f32(v2.x, v2.y, p2, false);
  p2 = __builtin_amdgcn_cvt_pk_fp8_f32(v2.z, v2.w, p2, true);
  p3 = __builtin_amdgcn_cvt_pk_fp8_f32(v3.x, v3.y, p3, false);
  p3 = __builtin_amdgcn_cvt_pk_fp8_f32(v3.z, v3.w, p3, true);
  *(v4i*)(wq + (long long)grp * 2048 + j * 1024 + l * 16) = (v4i){p0, p1, p2, p3};
}

// ---------------- LDS-staged fp8 GEMM, 256x128 block tile ----------------
// grid (NB, M/256), 256 threads = 4 waves 2x2 (wm: 128-row half, wn: 64-col
// half); wave tile 128x64 = Fa8 x Fb4 fragments.
__global__ __launch_bounds__(256, 2) void gemm_fp8_kernel(
    const unsigned char* __restrict__ xq, const unsigned char* __restrict__ wq,
    const float* __restrict__ xs_t /*[KB][M]*/,
    const float* __restrict__ wscale /*[NB][KB]*/,
    float* __restrict__ out) {
  __shared__ unsigned char Asm[16 * 2048];  // 32 KB: 16 A frag-groups
  __shared__ unsigned char Bsm[8 * 2048];   // 16 KB: 8 B frag-groups
  __shared__ float Stab[KB * 256];          // 32 KB: combined scales [kb][row]

  const int tid   = threadIdx.x;
  const int ntile = blockIdx.x;  // 0..31
  const int mtile = blockIdx.y;  // 0..31 (256-row tiles)
  const int wave  = tid >> 6;
  const int lane  = tid & 63;
  const int wm = wave >> 1, wn = wave & 1;
  const int l15 = lane & 15, quad = lane >> 4;

  // combined scales: Stab[kb*256 + r] = xs[mtile*256+r, kb] * wsc[ntile, kb]
  for (int i = tid; i < KB * 256; i += 256) {
    const int kb = i >> 8, r = i & 255;
    Stab[i] = xs_t[(long long)kb * M + mtile * 256 + r] * wscale[ntile * KB + kb];
  }

  // staging: wave stages A groups [wave*4, wave*4+4) and B groups [wave*2, +2)
  // global group base advances by 2048 B per kb (groups are kb-major inner).
  const unsigned char* pa0 =
      xq + ((long long)(mtile * 16 + wave * 4) * KB) * 2048 + lane * 16;
  const unsigned char* pb0 =
      wq + ((long long)(ntile * 8 + wave * 2) * KB) * 2048 + lane * 16;
  const int a_lds0 = wave * 4 * 2048;
  const int b_lds0 = wave * 2 * 2048;

  v4f acc[8][4];
#pragma unroll
  for (int f = 0; f < 8; ++f)
#pragma unroll
    for (int g = 0; g < 4; ++g) acc[f][g] = (v4f){0.f, 0.f, 0.f, 0.f};

  const v4f z = (v4f){0.f, 0.f, 0.f, 0.f};

#pragma unroll 1
  for (int kb = 0; kb < KB; ++kb) {
    const long long koff = (long long)kb * 2048;
    // ---- stage 48 KB: 12 contiguous 1KB DMAs per wave ----
#pragma unroll
    for (int t = 0; t < 8; ++t)  // A: group t>>1, half t&1
      async16(pa0 + koff + (long long)(t >> 1) * (KB * 2048) + (t & 1) * 1024,
              Asm + a_lds0 + (t >> 1) * 2048 + (t & 1) * 1024);
#pragma unroll
    for (int t = 0; t < 4; ++t)  // B: group t>>1, half t&1
      async16(pb0 + koff + (long long)(t >> 1) * (KB * 2048) + (t & 1) * 1024,
              Bsm + b_lds0 + (t >> 1) * 2048 + (t & 1) * 1024);
    __syncthreads();  // drain vmcnt: tiles (and, first iter, Stab) visible

    // ---- B fragments (shared across all f) ----
    v8i b[4];
#pragma unroll
    for (int g = 0; g < 4; ++g) {
      const unsigned char* pb = Bsm + (wn * 4 + g) * 2048 + lane * 16;
      v4i lo = *(const v4i*)pb;
      v4i hi = *(const v4i*)(pb + 1024);
      b[g][0] = lo[0]; b[g][1] = lo[1]; b[g][2] = lo[2]; b[g][3] = lo[3];
      b[g][4] = hi[0]; b[g][5] = hi[1]; b[g][6] = hi[2]; b[g][7] = hi[3];
    }

    // ---- per A-fragment: load, 4 MFMA, exact f32 rescale ----
#pragma unroll
    for (int f = 0; f < 8; ++f) {
      const unsigned char* pa = Asm + (wm * 8 + f) * 2048 + lane * 16;
      v4i lo = *(const v4i*)pa;
      v4i hi = *(const v4i*)(pa + 1024);
      v8i a;
      a[0] = lo[0]; a[1] = lo[1]; a[2] = lo[2]; a[3] = lo[3];
      a[4] = hi[0]; a[5] = hi[1]; a[6] = hi[2]; a[7] = hi[3];
      const v4f sx = *(const v4f*)(Stab + kb * 256 + wm * 128 + f * 16 + quad * 4);
#pragma unroll
      for (int g = 0; g < 4; ++g) {
        // unit e8m0 scales (0x7F = 2^0): plain fp8 K=128 dot at MX rate
        v4f p = __builtin_amdgcn_mfma_scale_f32_16x16x128_f8f6f4(
            a, b[g], z, 0, 0, 0, 0x7f7f7f7f, 0, 0x7f7f7f7f);
        acc[f][g] += sx * p;
      }
    }
    __syncthreads();  // all reads done: safe to overwrite tiles next iter
  }

  // ---- epilogue: C/D layout col = lane&15, row = quad*4 + reg ----
#pragma unroll
  for (int f = 0; f < 8; ++f) {
#pragma unroll
    for (int r = 0; r < 4; ++r) {
      const long long row = mtile * 256 + wm * 128 + f * 16 + quad * 4 + r;
      float* po = out + row * N + ntile * 128 + wn * 64 + l15;
#pragma unroll
      for (int g = 0; g < 4; ++g) po[g * 16] = acc[f][g][r];
    }
  }
}

extern "C" void kernel_launch(void* const* d_in, const int* in_sizes, int n_in,
                              void* d_out, int out_size, void* d_ws, size_t ws_size,
                              hipStream_t stream) {
  const float* x   = (const float*)d_in[0];  // [M,K]
  const float* w   = (const float*)d_in[1];  // [N,K]
  const float* wsc = (const float*)d_in[2];  // [NB,KB]
  float* out = (float*)d_out;                // [M,N] f32

  unsigned char* ws = (unsigned char*)d_ws;
  unsigned char* xq = ws;                                      // 32 MB frag-order
  unsigned char* wq = ws + (size_t)M * K;                      // 16 MB frag-order
  float* xs_t = (float*)(ws + (size_t)M * K + (size_t)N * K);  // 1 MB [KB][M]

  quant_x_kernel<<<(M * KB * 8) / 256, 256, 0, stream>>>(x, xq, xs_t);
  quant_w_kernel<<<(int)(((long long)N * K / 16) / 256), 256, 0, stream>>>(w, wq);
  gemm_fp8_kernel<<<dim3(NB, M / 256), 256, 0, stream>>>(xq, wq, xs_t, wsc, out);
}